// Round 1
// baseline (1656.752 us; speedup 1.0000x reference)
//
#include <hip/hip_runtime.h>
#include <math.h>

#define N_NODES 50000
#define N_EDGES 1600000
#define F_IN 128
#define C 64
#define EF 64
#define N_GRAPHS 512
#define MLP_DIM 128
#define N_CLASSES 10
#define EPS 1e-5f

// ============================ CSR build (counting sort by dst) ============================
__global__ void hist_kernel(const int* __restrict__ dst, int* __restrict__ cnt) {
    for (int e = blockIdx.x * blockDim.x + threadIdx.x; e < N_EDGES; e += gridDim.x * blockDim.x)
        atomicAdd(&cnt[dst[e]], 1);
}

__global__ void scan1_kernel(const int* __restrict__ cnt, int* __restrict__ row_start,
                             int* __restrict__ blocksum) {
    __shared__ int arr[1024];
    int tid = threadIdx.x;
    int idx = blockIdx.x * 1024 + tid;
    int v = (idx < N_NODES) ? cnt[idx] : 0;
    arr[tid] = v;
    __syncthreads();
    for (int off = 1; off < 1024; off <<= 1) {
        int t = (tid >= off) ? arr[tid - off] : 0;
        __syncthreads();
        arr[tid] += t;
        __syncthreads();
    }
    if (idx < N_NODES) row_start[idx] = arr[tid] - v;  // exclusive scan
    if (tid == 1023) blocksum[blockIdx.x] = arr[1023];
}

__global__ void scan2_kernel(int* blocksum, int nblocks, int* row_start) {
    if (threadIdx.x == 0 && blockIdx.x == 0) {
        int run = 0;
        for (int b = 0; b < nblocks; b++) { int t = blocksum[b]; blocksum[b] = run; run += t; }
        row_start[N_NODES] = N_EDGES;
    }
}

__global__ void scan3_kernel(int* row_start, const int* __restrict__ blocksum) {
    int idx = blockIdx.x * 1024 + threadIdx.x;
    if (idx < N_NODES) row_start[idx] += blocksum[blockIdx.x];
}

__global__ void scatter_kernel(const int* __restrict__ src, const int* __restrict__ dst,
                               const int* __restrict__ row_start, int* __restrict__ cursor,
                               int* __restrict__ sorted_src) {
    for (int e = blockIdx.x * blockDim.x + threadIdx.x; e < N_EDGES; e += gridDim.x * blockDim.x) {
        int d = dst[e];
        int p = row_start[d] + atomicAdd(&cursor[d], 1);
        sorted_src[p] = src[e];
    }
}

// ============================ fc0: h0 = x @ fc0_w + fc0_b ============================
__global__ __launch_bounds__(256) void fc0_kernel(const float* __restrict__ x,
                                                  const float* __restrict__ w,
                                                  const float* __restrict__ b,
                                                  float* __restrict__ h0) {
    __shared__ float wl[F_IN * C];  // 32 KiB
    __shared__ __align__(16) float xr[4][F_IN];
    int tid = threadIdx.x, lane = tid & 63, wid = tid >> 6;
    for (int i = tid; i < F_IN * C; i += 256) wl[i] = w[i];
    __syncthreads();
    float bj = b[lane];
    for (int n = blockIdx.x * 4 + wid; n < N_NODES; n += gridDim.x * 4) {
        xr[wid][lane]      = x[n * F_IN + lane];
        xr[wid][64 + lane] = x[n * F_IN + 64 + lane];
        const float4* x4 = (const float4*)xr[wid];
        float a0 = 0, a1 = 0, a2 = 0, a3 = 0;
#pragma unroll
        for (int k4 = 0; k4 < F_IN / 4; k4++) {
            float4 hv = x4[k4];
            a0 = fmaf(hv.x, wl[(4 * k4 + 0) * C + lane], a0);
            a1 = fmaf(hv.y, wl[(4 * k4 + 1) * C + lane], a1);
            a2 = fmaf(hv.z, wl[(4 * k4 + 2) * C + lane], a2);
            a3 = fmaf(hv.w, wl[(4 * k4 + 3) * C + lane], a3);
        }
        h0[n * C + lane] = (a0 + a1) + (a2 + a3) + bj;
    }
}

// ============================ BatchNorm statistics ============================
__global__ __launch_bounds__(256) void bnstat_kernel(const float* __restrict__ h, int ldh,
                                                     float* __restrict__ bns) {
    __shared__ float s1s[4][64], s2s[4][64];
    int tid = threadIdx.x, lane = tid & 63, wid = tid >> 6;
    float s1 = 0.f, s2 = 0.f;
    for (int n = blockIdx.x * 4 + wid; n < N_NODES; n += gridDim.x * 4) {
        float v = h[(size_t)n * ldh + lane];
        s1 += v; s2 += v * v;
    }
    s1s[wid][lane] = s1; s2s[wid][lane] = s2;
    __syncthreads();
    if (tid < 64) {
        float a  = s1s[0][tid] + s1s[1][tid] + s1s[2][tid] + s1s[3][tid];
        float c2 = s2s[0][tid] + s2s[1][tid] + s2s[2][tid] + s2s[3][tid];
        atomicAdd(&bns[tid], a);
        atomicAdd(&bns[64 + tid], c2);
    }
}

// ===== fold BN into effective edge-MLP layer-1 weights: WA = scale*(w1a-w1b), WB = scale*w1b =====
__global__ void prep_kernel(const float* __restrict__ bns, const float* __restrict__ g,
                            const float* __restrict__ bb, const float* __restrict__ w1,
                            const float* __restrict__ b1, float* __restrict__ WA,
                            float* __restrict__ WB, float* __restrict__ cAB) {
    __shared__ float scale[64], shift[64];
    int j = threadIdx.x;  // 64 threads
    float mu  = bns[j] * (1.0f / N_NODES);
    float var = bns[64 + j] * (1.0f / N_NODES) - mu * mu;
    float sc  = g[j] * rsqrtf(var + EPS);
    scale[j] = sc;
    shift[j] = bb[j] - mu * sc;
    __syncthreads();
    float ca = b1[j], cb = 0.f;
    for (int k = 0; k < 64; k++) {
        float wa_ = w1[k * EF + j];
        float wb_ = w1[(64 + k) * EF + j];
        float wd  = wa_ - wb_;
        WA[k * 64 + j] = scale[k] * wd;
        WB[k * 64 + j] = scale[k] * wb_;
        ca += shift[k] * wd;
        cb += shift[k] * wb_;
    }
    cAB[j] = ca;
    cAB[64 + j] = cb;
}

// ============ per-node tables: A = h@WA + cA, B = h@WB + cB ============
__global__ __launch_bounds__(256) void ab_kernel(const float* __restrict__ h, int ldh,
                                                 const float* __restrict__ WA,
                                                 const float* __restrict__ WB,
                                                 const float* __restrict__ cAB,
                                                 float* __restrict__ A, float* __restrict__ B) {
    __shared__ float wal[64 * 64], wbl[64 * 64];  // 32 KiB
    __shared__ __align__(16) float hr[4][64];
    int tid = threadIdx.x, lane = tid & 63, wid = tid >> 6;
    for (int i = tid; i < 4096; i += 256) { wal[i] = WA[i]; wbl[i] = WB[i]; }
    __syncthreads();
    float ca = cAB[lane], cb = cAB[64 + lane];
    for (int n = blockIdx.x * 4 + wid; n < N_NODES; n += gridDim.x * 4) {
        hr[wid][lane] = h[(size_t)n * ldh + lane];
        const float4* h4 = (const float4*)hr[wid];
        float accA = ca, accB = cb;
#pragma unroll
        for (int k4 = 0; k4 < 16; k4++) {
            float4 hv = h4[k4];
            accA = fmaf(hv.x, wal[(4 * k4 + 0) * 64 + lane], accA);
            accB = fmaf(hv.x, wbl[(4 * k4 + 0) * 64 + lane], accB);
            accA = fmaf(hv.y, wal[(4 * k4 + 1) * 64 + lane], accA);
            accB = fmaf(hv.y, wbl[(4 * k4 + 1) * 64 + lane], accB);
            accA = fmaf(hv.z, wal[(4 * k4 + 2) * 64 + lane], accA);
            accB = fmaf(hv.z, wbl[(4 * k4 + 2) * 64 + lane], accB);
            accA = fmaf(hv.w, wal[(4 * k4 + 3) * 64 + lane], accA);
            accB = fmaf(hv.w, wbl[(4 * k4 + 3) * 64 + lane], accB);
        }
        A[n * 64 + lane] = accA;
        B[n * 64 + lane] = accB;
    }
}

// ============ EdgeConv: per dst-node max over edges of relu(A[dst]+B[src]) @ w2 + b2 ============
__global__ __launch_bounds__(256) void edge_kernel(const float* __restrict__ A,
                                                   const float* __restrict__ B,
                                                   const int* __restrict__ row_start,
                                                   const int* __restrict__ sorted_src,
                                                   const float* __restrict__ w2,
                                                   const float* __restrict__ b2,
                                                   float* __restrict__ cat, int colofs) {
    __shared__ __align__(16) float h1s[4][64];
    int tid = threadIdx.x, lane = tid & 63, wid = tid >> 6;
    float w2r[64];  // w2[:, lane] held in registers
#pragma unroll
    for (int k = 0; k < 64; k++) w2r[k] = w2[k * 64 + lane];
    float b2j = b2[lane];
    for (int n = blockIdx.x * 4 + wid; n < N_NODES; n += gridDim.x * 4) {
        int beg = row_start[n], end = row_start[n + 1];
        float aj = A[n * 64 + lane];
        float rm = -INFINITY;
        for (int p = beg; p < end; p++) {
            int s = sorted_src[p];                       // wave-uniform broadcast load
            float h1 = fmaxf(aj + B[s * 64 + lane], 0.f);
            h1s[wid][lane] = h1;                         // wave-synchronous LDS staging
            const float4* h4 = (const float4*)h1s[wid];
            float a0 = 0, a1 = 0, a2 = 0, a3 = 0;
#pragma unroll
            for (int k4 = 0; k4 < 16; k4++) {
                float4 hv = h4[k4];                      // same-address broadcast ds_read_b128
                a0 = fmaf(hv.x, w2r[4 * k4 + 0], a0);
                a1 = fmaf(hv.y, w2r[4 * k4 + 1], a1);
                a2 = fmaf(hv.z, w2r[4 * k4 + 2], a2);
                a3 = fmaf(hv.w, w2r[4 * k4 + 3], a3);
            }
            rm = fmaxf(rm, (a0 + a1) + (a2 + a3));
        }
        // max with 0 folds: where(isfinite,agg,0) + outer relu   (-inf + b2 -> 0)
        cat[(size_t)n * 192 + colofs + lane] = fmaxf(rm + b2j, 0.f);
    }
}

// ============================ graph mean pool ============================
__global__ void pool_kernel(const float* __restrict__ cat, const int* __restrict__ batch,
                            float* __restrict__ pooled) {
    __shared__ int se[2];
    int g = blockIdx.x, tid = threadIdx.x;  // 192 threads
    if (tid < 2) {
        int target = g + tid;
        int lo = 0, hi = N_NODES;
        while (lo < hi) { int mid = (lo + hi) >> 1; if (batch[mid] < target) lo = mid + 1; else hi = mid; }
        se[tid] = lo;
    }
    __syncthreads();
    int s = se[0], e = se[1];
    float acc = 0.f;
    for (int r = s; r < e; r++) acc += cat[(size_t)r * 192 + tid];
    float denom = (e > s) ? (float)(e - s) : 1.0f;
    pooled[g * 192 + tid] = acc / denom;
}

// ============================ MLP head + log_softmax ============================
__global__ __launch_bounds__(128) void head_kernel(const float* __restrict__ pooled,
                                                   const float* __restrict__ fc1w,
                                                   const float* __restrict__ fc1b,
                                                   const float* __restrict__ fc2w,
                                                   const float* __restrict__ fc2b,
                                                   float* __restrict__ out) {
    __shared__ float p[192];
    __shared__ float hid[128];
    __shared__ float z[10];
    __shared__ float lse;
    int g = blockIdx.x, tid = threadIdx.x;
    for (int i = tid; i < 192; i += 128) p[i] = pooled[g * 192 + i];
    __syncthreads();
    float acc = fc1b[tid];
    for (int k = 0; k < 192; k++) acc = fmaf(p[k], fc1w[k * 128 + tid], acc);
    hid[tid] = fmaxf(acc, 0.f);
    __syncthreads();
    if (tid < N_CLASSES) {
        float a = fc2b[tid];
        for (int k = 0; k < 128; k++) a = fmaf(hid[k], fc2w[k * 10 + tid], a);
        z[tid] = a;
    }
    __syncthreads();
    if (tid == 0) {
        float m = z[0];
        for (int i = 1; i < 10; i++) m = fmaxf(m, z[i]);
        float s = 0.f;
        for (int i = 0; i < 10; i++) s += expf(z[i] - m);
        lse = m + logf(s);
    }
    __syncthreads();
    if (tid < N_CLASSES) out[g * 10 + tid] = z[tid] - lse;
}

// ============================ launch ============================
extern "C" void kernel_launch(void* const* d_in, const int* in_sizes, int n_in,
                              void* d_out, int out_size, void* d_ws, size_t ws_size,
                              hipStream_t stream) {
    (void)in_sizes; (void)n_in; (void)out_size; (void)ws_size;
    const float* x    = (const float*)d_in[0];
    const int*   ei   = (const int*)d_in[1];
    const int*   batch= (const int*)d_in[2];
    const float* fc0w = (const float*)d_in[3];
    const float* fc0b = (const float*)d_in[4];
    const float* fc1w = (const float*)d_in[5];
    const float* fc1b = (const float*)d_in[6];
    const float* fc2w = (const float*)d_in[7];
    const float* fc2b = (const float*)d_in[8];
    const int* src = ei;
    const int* dst = ei + N_EDGES;
    float* out = (float*)d_out;

    char* w = (char*)d_ws;
    size_t off = 0;
    auto alloc = [&](size_t bytes) -> void* {
        void* p = w + off;
        off = (off + bytes + 255) & ~(size_t)255;
        return p;
    };
    float* cat     = (float*)alloc((size_t)N_NODES * 192 * 4);   // 38.4 MB (holds xs concat)
    float* h0      = (float*)alloc((size_t)N_NODES * 64 * 4);    // 12.8 MB
    float* Ae      = (float*)alloc((size_t)N_NODES * 64 * 4);    // 12.8 MB
    float* Be      = (float*)alloc((size_t)N_NODES * 64 * 4);    // 12.8 MB
    int*   sorted_src = (int*)alloc((size_t)N_EDGES * 4);        // 6.4 MB
    int*   cnt     = (int*)alloc((size_t)N_NODES * 4);
    int*   cursor  = (int*)alloc((size_t)N_NODES * 4);
    int*   row_start = (int*)alloc((size_t)(N_NODES + 1) * 4);
    int*   blocksum  = (int*)alloc(64 * 4);
    float* bns     = (float*)alloc(128 * 4);
    float* WA      = (float*)alloc(4096 * 4);
    float* WB      = (float*)alloc(4096 * 4);
    float* cAB     = (float*)alloc(128 * 4);
    float* pooled  = (float*)alloc((size_t)N_GRAPHS * 192 * 4);

    // --- CSR build (recomputed every launch; edge_index is an input) ---
    hipMemsetAsync(cnt, 0, (size_t)N_NODES * 4, stream);
    hipMemsetAsync(cursor, 0, (size_t)N_NODES * 4, stream);
    hist_kernel<<<512, 256, 0, stream>>>(dst, cnt);
    scan1_kernel<<<49, 1024, 0, stream>>>(cnt, row_start, blocksum);
    scan2_kernel<<<1, 64, 0, stream>>>(blocksum, 49, row_start);
    scan3_kernel<<<49, 1024, 0, stream>>>(row_start, blocksum);
    scatter_kernel<<<512, 256, 0, stream>>>(src, dst, row_start, cursor, sorted_src);

    fc0_kernel<<<1024, 256, 0, stream>>>(x, fc0w, fc0b, h0);

    for (int blk = 0; blk < 3; blk++) {
        const float* g  = (const float*)d_in[9 + 6 * blk];
        const float* bb = (const float*)d_in[10 + 6 * blk];
        const float* w1 = (const float*)d_in[11 + 6 * blk];
        const float* b1 = (const float*)d_in[12 + 6 * blk];
        const float* w2 = (const float*)d_in[13 + 6 * blk];
        const float* b2 = (const float*)d_in[14 + 6 * blk];
        const float* hsrc = (blk == 0) ? h0 : (cat + (blk - 1) * 64);
        int ldh = (blk == 0) ? 64 : 192;

        hipMemsetAsync(bns, 0, 128 * 4, stream);
        bnstat_kernel<<<512, 256, 0, stream>>>(hsrc, ldh, bns);
        prep_kernel<<<1, 64, 0, stream>>>(bns, g, bb, w1, b1, WA, WB, cAB);
        ab_kernel<<<1024, 256, 0, stream>>>(hsrc, ldh, WA, WB, cAB, Ae, Be);
        edge_kernel<<<2048, 256, 0, stream>>>(Ae, Be, row_start, sorted_src, w2, b2, cat, blk * 64);
    }

    pool_kernel<<<N_GRAPHS, 192, 0, stream>>>(cat, batch, pooled);
    head_kernel<<<N_GRAPHS, 128, 0, stream>>>(pooled, fc1w, fc1b, fc2w, fc2b, out);
}

// Round 2
// 744.419 us; speedup vs baseline: 2.2256x; 2.2256x over previous
//
#include <hip/hip_runtime.h>
#include <math.h>

#define N_NODES 50000
#define N_EDGES 1600000
#define F_IN 128
#define C 64
#define EF 64
#define N_GRAPHS 512
#define MLP_DIM 128
#define N_CLASSES 10
#define EPS 1e-5f

typedef __attribute__((ext_vector_type(8))) short short8;   // 8 x bf16 (4 VGPRs)
typedef __attribute__((ext_vector_type(4))) float floatx4;  // MFMA acc

__device__ __forceinline__ unsigned pack2bf(float a, float b) {
    // round-half-up f32->bf16, pack pair (a=low, b=high)
    unsigned ua = __float_as_uint(a) + 0x8000u;
    unsigned ub = __float_as_uint(b) + 0x8000u;
    return (ua >> 16) | (ub & 0xFFFF0000u);
}

// ============================ CSR build (counting sort by dst, padded to 16) ============================
__global__ void hist_kernel(const int* __restrict__ dst, int* __restrict__ cnt) {
    for (int e = blockIdx.x * blockDim.x + threadIdx.x; e < N_EDGES; e += gridDim.x * blockDim.x)
        atomicAdd(&cnt[dst[e]], 1);
}

__global__ void scan1_kernel(const int* __restrict__ cnt, int* __restrict__ row_start,
                             int* __restrict__ blocksum) {
    __shared__ int arr[1024];
    int tid = threadIdx.x;
    int idx = blockIdx.x * 1024 + tid;
    int v = (idx < N_NODES) ? ((cnt[idx] + 15) & ~15) : 0;  // padded segment length
    arr[tid] = v;
    __syncthreads();
    for (int off = 1; off < 1024; off <<= 1) {
        int t = (tid >= off) ? arr[tid - off] : 0;
        __syncthreads();
        arr[tid] += t;
        __syncthreads();
    }
    if (idx < N_NODES) row_start[idx] = arr[tid] - v;  // exclusive scan
    if (tid == 1023) blocksum[blockIdx.x] = arr[1023];
}

__global__ void scan2_kernel(int* blocksum, int nblocks, int* row_start) {
    if (threadIdx.x == 0 && blockIdx.x == 0) {
        int run = 0;
        for (int b = 0; b < nblocks; b++) { int t = blocksum[b]; blocksum[b] = run; run += t; }
        row_start[N_NODES] = run;  // total padded edge count
    }
}

__global__ void scan3_kernel(int* row_start, const int* __restrict__ blocksum) {
    int idx = blockIdx.x * 1024 + threadIdx.x;
    if (idx < N_NODES) row_start[idx] += blocksum[blockIdx.x];
}

__global__ void scatter_kernel(const int* __restrict__ src, const int* __restrict__ dst,
                               const int* __restrict__ row_start, int* __restrict__ cursor,
                               int* __restrict__ sorted_src) {
    for (int e = blockIdx.x * blockDim.x + threadIdx.x; e < N_EDGES; e += gridDim.x * blockDim.x) {
        int d = dst[e];
        int p = row_start[d] + atomicAdd(&cursor[d], 1);
        sorted_src[p] = src[e];
    }
}

// pad tail of each node's segment with a duplicate of its first real src (max is idempotent)
__global__ void fill_kernel(const int* __restrict__ cnt, const int* __restrict__ row_start,
                            int* __restrict__ sorted_src) {
    int n = blockIdx.x * blockDim.x + threadIdx.x;
    if (n >= N_NODES) return;
    int deg = cnt[n];
    if (deg == 0) return;
    int beg = row_start[n];
    int end = row_start[n + 1];
    int s0 = sorted_src[beg];
    for (int p = beg + deg; p < end; p++) sorted_src[p] = s0;
}

// ============================ fc0: h0 = x @ fc0_w + fc0_b ============================
__global__ __launch_bounds__(256) void fc0_kernel(const float* __restrict__ x,
                                                  const float* __restrict__ w,
                                                  const float* __restrict__ b,
                                                  float* __restrict__ h0) {
    __shared__ float wl[F_IN * C];  // 32 KiB
    __shared__ __align__(16) float xr[4][F_IN];
    int tid = threadIdx.x, lane = tid & 63, wid = tid >> 6;
    for (int i = tid; i < F_IN * C; i += 256) wl[i] = w[i];
    __syncthreads();
    float bj = b[lane];
    for (int n = blockIdx.x * 4 + wid; n < N_NODES; n += gridDim.x * 4) {
        xr[wid][lane]      = x[n * F_IN + lane];
        xr[wid][64 + lane] = x[n * F_IN + 64 + lane];
        const float4* x4 = (const float4*)xr[wid];
        float a0 = 0, a1 = 0, a2 = 0, a3 = 0;
#pragma unroll
        for (int k4 = 0; k4 < F_IN / 4; k4++) {
            float4 hv = x4[k4];
            a0 = fmaf(hv.x, wl[(4 * k4 + 0) * C + lane], a0);
            a1 = fmaf(hv.y, wl[(4 * k4 + 1) * C + lane], a1);
            a2 = fmaf(hv.z, wl[(4 * k4 + 2) * C + lane], a2);
            a3 = fmaf(hv.w, wl[(4 * k4 + 3) * C + lane], a3);
        }
        h0[n * C + lane] = (a0 + a1) + (a2 + a3) + bj;
    }
}

// ============================ BatchNorm statistics ============================
__global__ __launch_bounds__(256) void bnstat_kernel(const float* __restrict__ h, int ldh,
                                                     float* __restrict__ bns) {
    __shared__ float s1s[4][64], s2s[4][64];
    int tid = threadIdx.x, lane = tid & 63, wid = tid >> 6;
    float s1 = 0.f, s2 = 0.f;
    for (int n = blockIdx.x * 4 + wid; n < N_NODES; n += gridDim.x * 4) {
        float v = h[(size_t)n * ldh + lane];
        s1 += v; s2 += v * v;
    }
    s1s[wid][lane] = s1; s2s[wid][lane] = s2;
    __syncthreads();
    if (tid < 64) {
        float a  = s1s[0][tid] + s1s[1][tid] + s1s[2][tid] + s1s[3][tid];
        float c2 = s2s[0][tid] + s2s[1][tid] + s2s[2][tid] + s2s[3][tid];
        atomicAdd(&bns[tid], a);
        atomicAdd(&bns[64 + tid], c2);
    }
}

// ===== fold BN into effective edge-MLP layer-1 weights: WA = scale*(w1a-w1b), WB = scale*w1b =====
__global__ void prep_kernel(const float* __restrict__ bns, const float* __restrict__ g,
                            const float* __restrict__ bb, const float* __restrict__ w1,
                            const float* __restrict__ b1, float* __restrict__ WA,
                            float* __restrict__ WB, float* __restrict__ cAB) {
    __shared__ float scale[64], shift[64];
    int j = threadIdx.x;  // 64 threads
    float mu  = bns[j] * (1.0f / N_NODES);
    float var = bns[64 + j] * (1.0f / N_NODES) - mu * mu;
    float sc  = g[j] * rsqrtf(var + EPS);
    scale[j] = sc;
    shift[j] = bb[j] - mu * sc;
    __syncthreads();
    float ca = b1[j], cb = 0.f;
    for (int k = 0; k < 64; k++) {
        float wa_ = w1[k * EF + j];
        float wb_ = w1[(64 + k) * EF + j];
        float wd  = wa_ - wb_;
        WA[k * 64 + j] = scale[k] * wd;
        WB[k * 64 + j] = scale[k] * wb_;
        ca += shift[k] * wd;
        cb += shift[k] * wb_;
    }
    cAB[j] = ca;
    cAB[64 + j] = cb;
}

// ============ per-node tables: A = h@WA + cA, B = h@WB + cB ============
__global__ __launch_bounds__(256) void ab_kernel(const float* __restrict__ h, int ldh,
                                                 const float* __restrict__ WA,
                                                 const float* __restrict__ WB,
                                                 const float* __restrict__ cAB,
                                                 float* __restrict__ A, float* __restrict__ B) {
    __shared__ float wal[64 * 64], wbl[64 * 64];  // 32 KiB
    __shared__ __align__(16) float hr[4][64];
    int tid = threadIdx.x, lane = tid & 63, wid = tid >> 6;
    for (int i = tid; i < 4096; i += 256) { wal[i] = WA[i]; wbl[i] = WB[i]; }
    __syncthreads();
    float ca = cAB[lane], cb = cAB[64 + lane];
    for (int n = blockIdx.x * 4 + wid; n < N_NODES; n += gridDim.x * 4) {
        hr[wid][lane] = h[(size_t)n * ldh + lane];
        const float4* h4 = (const float4*)hr[wid];
        float accA = ca, accB = cb;
#pragma unroll
        for (int k4 = 0; k4 < 16; k4++) {
            float4 hv = h4[k4];
            accA = fmaf(hv.x, wal[(4 * k4 + 0) * 64 + lane], accA);
            accB = fmaf(hv.x, wbl[(4 * k4 + 0) * 64 + lane], accB);
            accA = fmaf(hv.y, wal[(4 * k4 + 1) * 64 + lane], accA);
            accB = fmaf(hv.y, wbl[(4 * k4 + 1) * 64 + lane], accB);
            accA = fmaf(hv.z, wal[(4 * k4 + 2) * 64 + lane], accA);
            accB = fmaf(hv.z, wbl[(4 * k4 + 2) * 64 + lane], accB);
            accA = fmaf(hv.w, wal[(4 * k4 + 3) * 64 + lane], accA);
            accB = fmaf(hv.w, wbl[(4 * k4 + 3) * 64 + lane], accB);
        }
        A[n * 64 + lane] = accA;
        B[n * 64 + lane] = accB;
    }
}

// ============ EdgeConv via MFMA: tiles of 16 edges (node-pure), h1 @ w2, segmented max ============
// mfma_f32_16x16x32_bf16 layouts:
//   A (M=16 edges x K=32): lane holds A[m=lane&15][k=(lane>>4)*8 + j], j=0..7
//   B (K=32 x N=16 cols):  lane holds B[k=(lane>>4)*8 + j][n=lane&15]
//   C/D: col=lane&15, row=(lane>>4)*4+reg
__global__ __launch_bounds__(256) void edge_mfma_kernel(
        const float* __restrict__ A, const float* __restrict__ B,
        const int* __restrict__ row_start, const int* __restrict__ sorted_src,
        const float* __restrict__ w2, const float* __restrict__ b2,
        float* __restrict__ cat, int colofs) {
    int tid = threadIdx.x, lane = tid & 63, wid = tid >> 6;
    int kq = (lane >> 4) * 8;  // this lane's k-offset within each 32-chunk
    int cl = lane & 15;

    // w2 fragments, wave-invariant, held in registers (32 VGPRs)
    short8 bfr[2][4];
#pragma unroll
    for (int kh = 0; kh < 2; kh++)
#pragma unroll
        for (int cb = 0; cb < 4; cb++) {
            union { short8 s; unsigned u[4]; } f;
#pragma unroll
            for (int j = 0; j < 4; j++) {
                float w0 = w2[(kh * 32 + kq + 2 * j) * 64 + cb * 16 + cl];
                float w1 = w2[(kh * 32 + kq + 2 * j + 1) * 64 + cb * 16 + cl];
                f.u[j] = pack2bf(w0, w1);
            }
            bfr[kh][cb] = f.s;
        }
    float b2j = b2[lane];

    for (int n = blockIdx.x * 4 + wid; n < N_NODES; n += gridDim.x * 4) {
        int beg = row_start[n], end = row_start[n + 1];
        const float* arow = A + (size_t)n * 64 + kq;
        floatx4 an0 = *(const floatx4*)(arow);
        floatx4 an1 = *(const floatx4*)(arow + 4);
        floatx4 an2 = *(const floatx4*)(arow + 32);
        floatx4 an3 = *(const floatx4*)(arow + 36);
        floatx4 rmax0 = {-INFINITY, -INFINITY, -INFINITY, -INFINITY};
        floatx4 rmax1 = rmax0, rmax2 = rmax0, rmax3 = rmax0;

        for (int p0 = beg; p0 < end; p0 += 16) {
            int srcm = sorted_src[p0 + cl];  // edge row m = cl for this lane
            const float* brow = B + (size_t)srcm * 64 + kq;
            floatx4 b0 = *(const floatx4*)(brow);
            floatx4 b1 = *(const floatx4*)(brow + 4);
            floatx4 b2v = *(const floatx4*)(brow + 32);
            floatx4 b3v = *(const floatx4*)(brow + 36);
            union { short8 s; unsigned u[4]; } a0, a1;
            a0.u[0] = pack2bf(fmaxf(an0.x + b0.x, 0.f), fmaxf(an0.y + b0.y, 0.f));
            a0.u[1] = pack2bf(fmaxf(an0.z + b0.z, 0.f), fmaxf(an0.w + b0.w, 0.f));
            a0.u[2] = pack2bf(fmaxf(an1.x + b1.x, 0.f), fmaxf(an1.y + b1.y, 0.f));
            a0.u[3] = pack2bf(fmaxf(an1.z + b1.z, 0.f), fmaxf(an1.w + b1.w, 0.f));
            a1.u[0] = pack2bf(fmaxf(an2.x + b2v.x, 0.f), fmaxf(an2.y + b2v.y, 0.f));
            a1.u[1] = pack2bf(fmaxf(an2.z + b2v.z, 0.f), fmaxf(an2.w + b2v.w, 0.f));
            a1.u[2] = pack2bf(fmaxf(an3.x + b3v.x, 0.f), fmaxf(an3.y + b3v.y, 0.f));
            a1.u[3] = pack2bf(fmaxf(an3.z + b3v.z, 0.f), fmaxf(an3.w + b3v.w, 0.f));

            floatx4 acc0 = {0.f, 0.f, 0.f, 0.f}, acc1 = acc0, acc2 = acc0, acc3 = acc0;
            acc0 = __builtin_amdgcn_mfma_f32_16x16x32_bf16(a0.s, bfr[0][0], acc0, 0, 0, 0);
            acc1 = __builtin_amdgcn_mfma_f32_16x16x32_bf16(a0.s, bfr[0][1], acc1, 0, 0, 0);
            acc2 = __builtin_amdgcn_mfma_f32_16x16x32_bf16(a0.s, bfr[0][2], acc2, 0, 0, 0);
            acc3 = __builtin_amdgcn_mfma_f32_16x16x32_bf16(a0.s, bfr[0][3], acc3, 0, 0, 0);
            acc0 = __builtin_amdgcn_mfma_f32_16x16x32_bf16(a1.s, bfr[1][0], acc0, 0, 0, 0);
            acc1 = __builtin_amdgcn_mfma_f32_16x16x32_bf16(a1.s, bfr[1][1], acc1, 0, 0, 0);
            acc2 = __builtin_amdgcn_mfma_f32_16x16x32_bf16(a1.s, bfr[1][2], acc2, 0, 0, 0);
            acc3 = __builtin_amdgcn_mfma_f32_16x16x32_bf16(a1.s, bfr[1][3], acc3, 0, 0, 0);

            rmax0.x = fmaxf(rmax0.x, acc0.x); rmax0.y = fmaxf(rmax0.y, acc0.y);
            rmax0.z = fmaxf(rmax0.z, acc0.z); rmax0.w = fmaxf(rmax0.w, acc0.w);
            rmax1.x = fmaxf(rmax1.x, acc1.x); rmax1.y = fmaxf(rmax1.y, acc1.y);
            rmax1.z = fmaxf(rmax1.z, acc1.z); rmax1.w = fmaxf(rmax1.w, acc1.w);
            rmax2.x = fmaxf(rmax2.x, acc2.x); rmax2.y = fmaxf(rmax2.y, acc2.y);
            rmax2.z = fmaxf(rmax2.z, acc2.z); rmax2.w = fmaxf(rmax2.w, acc2.w);
            rmax3.x = fmaxf(rmax3.x, acc3.x); rmax3.y = fmaxf(rmax3.y, acc3.y);
            rmax3.z = fmaxf(rmax3.z, acc3.z); rmax3.w = fmaxf(rmax3.w, acc3.w);
        }

        // reduce 16 edge-rows: 4 regs in-lane, then across the 4 lane-groups (same col)
        float v0 = fmaxf(fmaxf(rmax0.x, rmax0.y), fmaxf(rmax0.z, rmax0.w));
        float v1 = fmaxf(fmaxf(rmax1.x, rmax1.y), fmaxf(rmax1.z, rmax1.w));
        float v2 = fmaxf(fmaxf(rmax2.x, rmax2.y), fmaxf(rmax2.z, rmax2.w));
        float v3 = fmaxf(fmaxf(rmax3.x, rmax3.y), fmaxf(rmax3.z, rmax3.w));
        v0 = fmaxf(v0, __shfl_xor(v0, 16)); v0 = fmaxf(v0, __shfl_xor(v0, 32));
        v1 = fmaxf(v1, __shfl_xor(v1, 16)); v1 = fmaxf(v1, __shfl_xor(v1, 32));
        v2 = fmaxf(v2, __shfl_xor(v2, 16)); v2 = fmaxf(v2, __shfl_xor(v2, 32));
        v3 = fmaxf(v3, __shfl_xor(v3, 16)); v3 = fmaxf(v3, __shfl_xor(v3, 32));
        // lane's output col = lane = (lane>>4)*16 + cl  -> pick col-block lane>>4
        float vs = (lane & 32) ? ((lane & 16) ? v3 : v2) : ((lane & 16) ? v1 : v0);
        // where(isfinite,agg,0)+relu folds to fmax(.,0); empty node: -inf -> 0
        cat[(size_t)n * 192 + colofs + lane] = fmaxf(vs + b2j, 0.f);
    }
}

// ============================ graph mean pool ============================
__global__ void pool_kernel(const float* __restrict__ cat, const int* __restrict__ batch,
                            float* __restrict__ pooled) {
    __shared__ int se[2];
    int g = blockIdx.x, tid = threadIdx.x;  // 192 threads
    if (tid < 2) {
        int target = g + tid;
        int lo = 0, hi = N_NODES;
        while (lo < hi) { int mid = (lo + hi) >> 1; if (batch[mid] < target) lo = mid + 1; else hi = mid; }
        se[tid] = lo;
    }
    __syncthreads();
    int s = se[0], e = se[1];
    float acc = 0.f;
    for (int r = s; r < e; r++) acc += cat[(size_t)r * 192 + tid];
    float denom = (e > s) ? (float)(e - s) : 1.0f;
    pooled[g * 192 + tid] = acc / denom;
}

// ============================ MLP head + log_softmax ============================
__global__ __launch_bounds__(128) void head_kernel(const float* __restrict__ pooled,
                                                   const float* __restrict__ fc1w,
                                                   const float* __restrict__ fc1b,
                                                   const float* __restrict__ fc2w,
                                                   const float* __restrict__ fc2b,
                                                   float* __restrict__ out) {
    __shared__ float p[192];
    __shared__ float hid[128];
    __shared__ float z[10];
    __shared__ float lse;
    int g = blockIdx.x, tid = threadIdx.x;
    for (int i = tid; i < 192; i += 128) p[i] = pooled[g * 192 + i];
    __syncthreads();
    float acc = fc1b[tid];
    for (int k = 0; k < 192; k++) acc = fmaf(p[k], fc1w[k * 128 + tid], acc);
    hid[tid] = fmaxf(acc, 0.f);
    __syncthreads();
    if (tid < N_CLASSES) {
        float a = fc2b[tid];
        for (int k = 0; k < 128; k++) a = fmaf(hid[k], fc2w[k * 10 + tid], a);
        z[tid] = a;
    }
    __syncthreads();
    if (tid == 0) {
        float m = z[0];
        for (int i = 1; i < 10; i++) m = fmaxf(m, z[i]);
        float s = 0.f;
        for (int i = 0; i < 10; i++) s += expf(z[i] - m);
        lse = m + logf(s);
    }
    __syncthreads();
    if (tid < N_CLASSES) out[g * 10 + tid] = z[tid] - lse;
}

// ============================ launch ============================
extern "C" void kernel_launch(void* const* d_in, const int* in_sizes, int n_in,
                              void* d_out, int out_size, void* d_ws, size_t ws_size,
                              hipStream_t stream) {
    (void)in_sizes; (void)n_in; (void)out_size; (void)ws_size;
    const float* x    = (const float*)d_in[0];
    const int*   ei   = (const int*)d_in[1];
    const int*   batch= (const int*)d_in[2];
    const float* fc0w = (const float*)d_in[3];
    const float* fc0b = (const float*)d_in[4];
    const float* fc1w = (const float*)d_in[5];
    const float* fc1b = (const float*)d_in[6];
    const float* fc2w = (const float*)d_in[7];
    const float* fc2b = (const float*)d_in[8];
    const int* src = ei;
    const int* dst = ei + N_EDGES;
    float* out = (float*)d_out;

    char* w = (char*)d_ws;
    size_t off = 0;
    auto alloc = [&](size_t bytes) -> void* {
        void* p = w + off;
        off = (off + bytes + 255) & ~(size_t)255;
        return p;
    };
    const size_t MAX_PAD_EDGES = (size_t)N_EDGES + 16 * (size_t)N_NODES;  // worst case
    float* cat     = (float*)alloc((size_t)N_NODES * 192 * 4);   // 38.4 MB
    float* h0      = (float*)alloc((size_t)N_NODES * 64 * 4);    // 12.8 MB
    float* Ae      = (float*)alloc((size_t)N_NODES * 64 * 4);    // 12.8 MB
    float* Be      = (float*)alloc((size_t)N_NODES * 64 * 4);    // 12.8 MB
    int*   sorted_src = (int*)alloc(MAX_PAD_EDGES * 4);          // 9.6 MB
    int*   cnt     = (int*)alloc((size_t)N_NODES * 4);
    int*   cursor  = (int*)alloc((size_t)N_NODES * 4);
    int*   row_start = (int*)alloc((size_t)(N_NODES + 1) * 4);
    int*   blocksum  = (int*)alloc(64 * 4);
    float* bns     = (float*)alloc(128 * 4);
    float* WA      = (float*)alloc(4096 * 4);
    float* WB      = (float*)alloc(4096 * 4);
    float* cAB     = (float*)alloc(128 * 4);
    float* pooled  = (float*)alloc((size_t)N_GRAPHS * 192 * 4);

    // --- padded CSR build ---
    hipMemsetAsync(cnt, 0, (size_t)N_NODES * 4, stream);
    hipMemsetAsync(cursor, 0, (size_t)N_NODES * 4, stream);
    hist_kernel<<<512, 256, 0, stream>>>(dst, cnt);
    scan1_kernel<<<49, 1024, 0, stream>>>(cnt, row_start, blocksum);
    scan2_kernel<<<1, 64, 0, stream>>>(blocksum, 49, row_start);
    scan3_kernel<<<49, 1024, 0, stream>>>(row_start, blocksum);
    scatter_kernel<<<512, 256, 0, stream>>>(src, dst, row_start, cursor, sorted_src);
    fill_kernel<<<(N_NODES + 255) / 256, 256, 0, stream>>>(cnt, row_start, sorted_src);

    fc0_kernel<<<1024, 256, 0, stream>>>(x, fc0w, fc0b, h0);

    for (int blk = 0; blk < 3; blk++) {
        const float* g  = (const float*)d_in[9 + 6 * blk];
        const float* bb = (const float*)d_in[10 + 6 * blk];
        const float* w1 = (const float*)d_in[11 + 6 * blk];
        const float* b1 = (const float*)d_in[12 + 6 * blk];
        const float* w2 = (const float*)d_in[13 + 6 * blk];
        const float* b2 = (const float*)d_in[14 + 6 * blk];
        const float* hsrc = (blk == 0) ? h0 : (cat + (blk - 1) * 64);
        int ldh = (blk == 0) ? 64 : 192;

        hipMemsetAsync(bns, 0, 128 * 4, stream);
        bnstat_kernel<<<512, 256, 0, stream>>>(hsrc, ldh, bns);
        prep_kernel<<<1, 64, 0, stream>>>(bns, g, bb, w1, b1, WA, WB, cAB);
        ab_kernel<<<1024, 256, 0, stream>>>(hsrc, ldh, WA, WB, cAB, Ae, Be);
        edge_mfma_kernel<<<2048, 256, 0, stream>>>(Ae, Be, row_start, sorted_src, w2, b2, cat, blk * 64);
    }

    pool_kernel<<<N_GRAPHS, 192, 0, stream>>>(cat, batch, pooled);
    head_kernel<<<N_GRAPHS, 128, 0, stream>>>(pooled, fc1w, fc1b, fc2w, fc2b, out);
}

// Round 3
// 603.663 us; speedup vs baseline: 2.7445x; 1.2332x over previous
//
#include <hip/hip_runtime.h>
#include <math.h>

#define N_NODES 50000
#define N_EDGES 1600000
#define F_IN 128
#define C 64
#define EF 64
#define N_GRAPHS 512
#define MLP_DIM 128
#define N_CLASSES 10
#define EPS 1e-5f
#define NB 196            // coarse buckets: dst>>8, 256 nodes each (196*256 >= 50000)
#define CHUNK 4096        // edges per pass-1 block

typedef __attribute__((ext_vector_type(8))) short short8;   // 8 x bf16 (4 VGPRs)
typedef __attribute__((ext_vector_type(4))) float floatx4;  // MFMA acc
typedef __attribute__((ext_vector_type(4))) unsigned uintx4;

__device__ __forceinline__ unsigned pack2bf(float a, float b) {
    // round-half-up f32->bf16, pack pair (a=low, b=high)
    unsigned ua = __float_as_uint(a) + 0x8000u;
    unsigned ub = __float_as_uint(b) + 0x8000u;
    return (ua >> 16) | (ub & 0xFFFF0000u);
}

// ==================== sort pass 0: per-bucket edge counts ====================
__global__ __launch_bounds__(256) void precount_kernel(const int* __restrict__ dst,
                                                       int* __restrict__ bucket_cnt) {
    __shared__ int lc[NB];
    int tid = threadIdx.x;
    for (int i = tid; i < NB; i += 256) lc[i] = 0;
    __syncthreads();
    for (int e = blockIdx.x * 256 + tid; e < N_EDGES; e += gridDim.x * 256)
        atomicAdd(&lc[dst[e] >> 8], 1);
    __syncthreads();
    for (int i = tid; i < NB; i += 256)
        if (lc[i]) atomicAdd(&bucket_cnt[i], lc[i]);
}

// exclusive scan of bucket counts -> bucket_start[0..NB], gcursor
__global__ void bucket_scan_kernel(const int* __restrict__ bucket_cnt,
                                   int* __restrict__ bucket_start, int* __restrict__ gcur) {
    __shared__ int a[256];
    int tid = threadIdx.x;
    int v = (tid < NB) ? bucket_cnt[tid] : 0;
    a[tid] = v;
    __syncthreads();
    for (int off = 1; off < 256; off <<= 1) {
        int t = (tid >= off) ? a[tid - off] : 0;
        __syncthreads();
        a[tid] += t;
        __syncthreads();
    }
    int excl = a[tid] - v;
    if (tid < NB) { bucket_start[tid] = excl; gcur[tid] = excl; }
    if (tid == NB - 1) bucket_start[NB] = excl + v;
}

// ==================== sort pass 1: bin edges into coarse buckets ====================
__global__ __launch_bounds__(256) void pass1_kernel(const int* __restrict__ src,
                                                    const int* __restrict__ dst,
                                                    int* __restrict__ gcur,
                                                    unsigned* __restrict__ keys) {
    __shared__ int lcnt[NB], lbase[NB], lcnt2[NB];
    int tid = threadIdx.x;
    int e0 = blockIdx.x * CHUNK;
    unsigned k[CHUNK / 256];
    int bk[CHUNK / 256];
    for (int i = tid; i < NB; i += 256) lcnt[i] = 0;
    __syncthreads();
#pragma unroll
    for (int i = 0; i < CHUNK / 256; i++) {
        int e = e0 + i * 256 + tid;
        if (e < N_EDGES) {
            int d = dst[e];
            k[i] = ((unsigned)d << 16) | (unsigned)src[e];
            bk[i] = d >> 8;
            atomicAdd(&lcnt[bk[i]], 1);
        } else bk[i] = -1;
    }
    __syncthreads();
    for (int i = tid; i < NB; i += 256) {
        int c = lcnt[i];
        lbase[i] = c ? atomicAdd(&gcur[i], c) : 0;
        lcnt2[i] = 0;
    }
    __syncthreads();
#pragma unroll
    for (int i = 0; i < CHUNK / 256; i++) {
        if (bk[i] >= 0) {
            int r = atomicAdd(&lcnt2[bk[i]], 1);
            keys[lbase[bk[i]] + r] = k[i];
        }
    }
}

// ==================== per-node degree from binned keys (no global atomics) ====================
__global__ __launch_bounds__(256) void node_count_kernel(const unsigned* __restrict__ keys,
                                                         const int* __restrict__ bucket_start,
                                                         int* __restrict__ cnt) {
    __shared__ int lc[256];
    int tid = threadIdx.x, b = blockIdx.x;
    lc[tid] = 0;
    __syncthreads();
    int beg = bucket_start[b], end = bucket_start[b + 1];
    for (int p = beg + tid; p < end; p += 256)
        atomicAdd(&lc[(keys[p] >> 16) & 255], 1);
    __syncthreads();
    int node = b * 256 + tid;
    if (node < N_NODES) cnt[node] = lc[tid];
}

// ==================== scans over padded per-node counts -> row_start ====================
__global__ void scan1_kernel(const int* __restrict__ cnt, int* __restrict__ row_start,
                             int* __restrict__ blocksum) {
    __shared__ int arr[1024];
    int tid = threadIdx.x;
    int idx = blockIdx.x * 1024 + tid;
    int v = (idx < N_NODES) ? ((cnt[idx] + 15) & ~15) : 0;  // padded segment length
    arr[tid] = v;
    __syncthreads();
    for (int off = 1; off < 1024; off <<= 1) {
        int t = (tid >= off) ? arr[tid - off] : 0;
        __syncthreads();
        arr[tid] += t;
        __syncthreads();
    }
    if (idx < N_NODES) row_start[idx] = arr[tid] - v;  // exclusive scan
    if (tid == 1023) blocksum[blockIdx.x] = arr[1023];
}

__global__ void scan2_kernel(int* blocksum, int nblocks, int* row_start) {
    if (threadIdx.x == 0 && blockIdx.x == 0) {
        int run = 0;
        for (int b = 0; b < nblocks; b++) { int t = blocksum[b]; blocksum[b] = run; run += t; }
        row_start[N_NODES] = run;  // total padded edge count
    }
}

__global__ void scan3_kernel(int* row_start, const int* __restrict__ blocksum) {
    int idx = blockIdx.x * 1024 + threadIdx.x;
    if (idx < N_NODES) row_start[idx] += blocksum[blockIdx.x];
}

// ==================== sort pass 2: block-local scatter into padded CSR + pad fill ====================
__global__ __launch_bounds__(256) void pass2_kernel(const unsigned* __restrict__ keys,
                                                    const int* __restrict__ bucket_start,
                                                    const int* __restrict__ row_start,
                                                    unsigned short* __restrict__ sorted_src) {
    __shared__ int cur[256];
    int tid = threadIdx.x, b = blockIdx.x;
    cur[tid] = 0;
    __syncthreads();
    int beg = bucket_start[b], end = bucket_start[b + 1];
    for (int p = beg + tid; p < end; p += 256) {
        unsigned k = keys[p];
        int n = k >> 16;
        int r = atomicAdd(&cur[n & 255], 1);
        sorted_src[row_start[n] + r] = (unsigned short)(k & 0xFFFFu);
    }
    __syncthreads();
    int node = b * 256 + tid;
    if (node < N_NODES) {
        int deg = cur[tid];
        if (deg > 0) {
            int rs = row_start[node], re = row_start[node + 1];
            unsigned short s0 = sorted_src[rs];
            for (int p = rs + deg; p < re; p++) sorted_src[p] = s0;  // max is idempotent
        }
    }
}

// ============================ fc0: h0 = x @ fc0_w + fc0_b ============================
__global__ __launch_bounds__(256) void fc0_kernel(const float* __restrict__ x,
                                                  const float* __restrict__ w,
                                                  const float* __restrict__ b,
                                                  float* __restrict__ h0) {
    __shared__ float wl[F_IN * C];  // 32 KiB
    __shared__ __align__(16) float xr[4][F_IN];
    int tid = threadIdx.x, lane = tid & 63, wid = tid >> 6;
    for (int i = tid; i < F_IN * C; i += 256) wl[i] = w[i];
    __syncthreads();
    float bj = b[lane];
    for (int n = blockIdx.x * 4 + wid; n < N_NODES; n += gridDim.x * 4) {
        xr[wid][lane]      = x[n * F_IN + lane];
        xr[wid][64 + lane] = x[n * F_IN + 64 + lane];
        const float4* x4 = (const float4*)xr[wid];
        float a0 = 0, a1 = 0, a2 = 0, a3 = 0;
#pragma unroll
        for (int k4 = 0; k4 < F_IN / 4; k4++) {
            float4 hv = x4[k4];
            a0 = fmaf(hv.x, wl[(4 * k4 + 0) * C + lane], a0);
            a1 = fmaf(hv.y, wl[(4 * k4 + 1) * C + lane], a1);
            a2 = fmaf(hv.z, wl[(4 * k4 + 2) * C + lane], a2);
            a3 = fmaf(hv.w, wl[(4 * k4 + 3) * C + lane], a3);
        }
        h0[n * C + lane] = (a0 + a1) + (a2 + a3) + bj;
    }
}

// ============================ BatchNorm statistics ============================
__global__ __launch_bounds__(256) void bnstat_kernel(const float* __restrict__ h, int ldh,
                                                     float* __restrict__ bns) {
    __shared__ float s1s[4][64], s2s[4][64];
    int tid = threadIdx.x, lane = tid & 63, wid = tid >> 6;
    float s1 = 0.f, s2 = 0.f;
    for (int n = blockIdx.x * 4 + wid; n < N_NODES; n += gridDim.x * 4) {
        float v = h[(size_t)n * ldh + lane];
        s1 += v; s2 += v * v;
    }
    s1s[wid][lane] = s1; s2s[wid][lane] = s2;
    __syncthreads();
    if (tid < 64) {
        float a  = s1s[0][tid] + s1s[1][tid] + s1s[2][tid] + s1s[3][tid];
        float c2 = s2s[0][tid] + s2s[1][tid] + s2s[2][tid] + s2s[3][tid];
        atomicAdd(&bns[tid], a);
        atomicAdd(&bns[64 + tid], c2);
    }
}

// ===== fold BN into effective edge-MLP layer-1 weights: WA = scale*(w1a-w1b), WB = scale*w1b =====
__global__ void prep_kernel(const float* __restrict__ bns, const float* __restrict__ g,
                            const float* __restrict__ bb, const float* __restrict__ w1,
                            const float* __restrict__ b1, float* __restrict__ WA,
                            float* __restrict__ WB, float* __restrict__ cAB) {
    __shared__ float scale[64], shift[64];
    int j = threadIdx.x;  // 64 threads
    float mu  = bns[j] * (1.0f / N_NODES);
    float var = bns[64 + j] * (1.0f / N_NODES) - mu * mu;
    float sc  = g[j] * rsqrtf(var + EPS);
    scale[j] = sc;
    shift[j] = bb[j] - mu * sc;
    __syncthreads();
    float ca = b1[j], cb = 0.f;
    for (int k = 0; k < 64; k++) {
        float wa_ = w1[k * EF + j];
        float wb_ = w1[(64 + k) * EF + j];
        float wd  = wa_ - wb_;
        WA[k * 64 + j] = scale[k] * wd;
        WB[k * 64 + j] = scale[k] * wb_;
        ca += shift[k] * wd;
        cb += shift[k] * wb_;
    }
    cAB[j] = ca;
    cAB[64 + j] = cb;
}

// ============ per-node tables: A = h@WA + cA (f32), B = h@WB + cB (bf16) ============
__global__ __launch_bounds__(256) void ab_kernel(const float* __restrict__ h, int ldh,
                                                 const float* __restrict__ WA,
                                                 const float* __restrict__ WB,
                                                 const float* __restrict__ cAB,
                                                 float* __restrict__ A,
                                                 unsigned short* __restrict__ Bb) {
    __shared__ float wal[64 * 64], wbl[64 * 64];  // 32 KiB
    __shared__ __align__(16) float hr[4][64];
    int tid = threadIdx.x, lane = tid & 63, wid = tid >> 6;
    for (int i = tid; i < 4096; i += 256) { wal[i] = WA[i]; wbl[i] = WB[i]; }
    __syncthreads();
    float ca = cAB[lane], cb = cAB[64 + lane];
    for (int n = blockIdx.x * 4 + wid; n < N_NODES; n += gridDim.x * 4) {
        hr[wid][lane] = h[(size_t)n * ldh + lane];
        const float4* h4 = (const float4*)hr[wid];
        float accA = ca, accB = cb;
#pragma unroll
        for (int k4 = 0; k4 < 16; k4++) {
            float4 hv = h4[k4];
            accA = fmaf(hv.x, wal[(4 * k4 + 0) * 64 + lane], accA);
            accB = fmaf(hv.x, wbl[(4 * k4 + 0) * 64 + lane], accB);
            accA = fmaf(hv.y, wal[(4 * k4 + 1) * 64 + lane], accA);
            accB = fmaf(hv.y, wbl[(4 * k4 + 1) * 64 + lane], accB);
            accA = fmaf(hv.z, wal[(4 * k4 + 2) * 64 + lane], accA);
            accB = fmaf(hv.z, wbl[(4 * k4 + 2) * 64 + lane], accB);
            accA = fmaf(hv.w, wal[(4 * k4 + 3) * 64 + lane], accA);
            accB = fmaf(hv.w, wbl[(4 * k4 + 3) * 64 + lane], accB);
        }
        A[n * 64 + lane] = accA;
        Bb[n * 64 + lane] = (unsigned short)((__float_as_uint(accB) + 0x8000u) >> 16);
    }
}

// ============ EdgeConv via MFMA: tiles of 16 edges (node-pure), h1 @ w2, segmented max ============
__global__ __launch_bounds__(256) void edge_mfma_kernel(
        const float* __restrict__ A, const unsigned short* __restrict__ Bb,
        const int* __restrict__ row_start, const unsigned short* __restrict__ sorted_src,
        const float* __restrict__ w2, const float* __restrict__ b2,
        float* __restrict__ cat, int colofs) {
    int tid = threadIdx.x, lane = tid & 63, wid = tid >> 6;
    int kq = (lane >> 4) * 8;  // this lane's k-offset within each 32-chunk
    int cl = lane & 15;

    // w2 fragments, wave-invariant, held in registers (32 VGPRs)
    short8 bfr[2][4];
#pragma unroll
    for (int kh = 0; kh < 2; kh++)
#pragma unroll
        for (int cb = 0; cb < 4; cb++) {
            union { short8 s; unsigned u[4]; } f;
#pragma unroll
            for (int j = 0; j < 4; j++) {
                float w0 = w2[(kh * 32 + kq + 2 * j) * 64 + cb * 16 + cl];
                float w1 = w2[(kh * 32 + kq + 2 * j + 1) * 64 + cb * 16 + cl];
                f.u[j] = pack2bf(w0, w1);
            }
            bfr[kh][cb] = f.s;
        }
    float b2j = b2[lane];

    for (int n = blockIdx.x * 4 + wid; n < N_NODES; n += gridDim.x * 4) {
        int beg = row_start[n], end = row_start[n + 1];
        const float* arow = A + (size_t)n * 64 + kq;
        floatx4 an0 = *(const floatx4*)(arow);
        floatx4 an1 = *(const floatx4*)(arow + 4);
        floatx4 an2 = *(const floatx4*)(arow + 32);
        floatx4 an3 = *(const floatx4*)(arow + 36);
        floatx4 rmax0 = {-INFINITY, -INFINITY, -INFINITY, -INFINITY};
        floatx4 rmax1 = rmax0, rmax2 = rmax0, rmax3 = rmax0;

        for (int p0 = beg; p0 < end; p0 += 16) {
            int srcm = sorted_src[p0 + cl];  // edge row m = cl for this lane
            const unsigned short* brow = Bb + (size_t)srcm * 64 + kq;
            uintx4 u0 = *(const uintx4*)(brow);       // bf16 x8: k = kq..kq+7
            uintx4 u1 = *(const uintx4*)(brow + 32);  // bf16 x8: k = 32+kq..32+kq+7
            union { short8 s; unsigned u[4]; } a0, a1;
#pragma unroll
            for (int j = 0; j < 4; j++) {
                float blo0 = __uint_as_float(u0[j] << 16);
                float bhi0 = __uint_as_float(u0[j] & 0xFFFF0000u);
                float blo1 = __uint_as_float(u1[j] << 16);
                float bhi1 = __uint_as_float(u1[j] & 0xFFFF0000u);
                float aL0 = (j < 2) ? ((j == 0) ? an0.x : an0.z) : ((j == 2) ? an1.x : an1.z);
                float aH0 = (j < 2) ? ((j == 0) ? an0.y : an0.w) : ((j == 2) ? an1.y : an1.w);
                float aL1 = (j < 2) ? ((j == 0) ? an2.x : an2.z) : ((j == 2) ? an3.x : an3.z);
                float aH1 = (j < 2) ? ((j == 0) ? an2.y : an2.w) : ((j == 2) ? an3.y : an3.w);
                a0.u[j] = pack2bf(fmaxf(aL0 + blo0, 0.f), fmaxf(aH0 + bhi0, 0.f));
                a1.u[j] = pack2bf(fmaxf(aL1 + blo1, 0.f), fmaxf(aH1 + bhi1, 0.f));
            }

            floatx4 acc0 = {0.f, 0.f, 0.f, 0.f}, acc1 = acc0, acc2 = acc0, acc3 = acc0;
            acc0 = __builtin_amdgcn_mfma_f32_16x16x32_bf16(a0.s, bfr[0][0], acc0, 0, 0, 0);
            acc1 = __builtin_amdgcn_mfma_f32_16x16x32_bf16(a0.s, bfr[0][1], acc1, 0, 0, 0);
            acc2 = __builtin_amdgcn_mfma_f32_16x16x32_bf16(a0.s, bfr[0][2], acc2, 0, 0, 0);
            acc3 = __builtin_amdgcn_mfma_f32_16x16x32_bf16(a0.s, bfr[0][3], acc3, 0, 0, 0);
            acc0 = __builtin_amdgcn_mfma_f32_16x16x32_bf16(a1.s, bfr[1][0], acc0, 0, 0, 0);
            acc1 = __builtin_amdgcn_mfma_f32_16x16x32_bf16(a1.s, bfr[1][1], acc1, 0, 0, 0);
            acc2 = __builtin_amdgcn_mfma_f32_16x16x32_bf16(a1.s, bfr[1][2], acc2, 0, 0, 0);
            acc3 = __builtin_amdgcn_mfma_f32_16x16x32_bf16(a1.s, bfr[1][3], acc3, 0, 0, 0);

            rmax0.x = fmaxf(rmax0.x, acc0.x); rmax0.y = fmaxf(rmax0.y, acc0.y);
            rmax0.z = fmaxf(rmax0.z, acc0.z); rmax0.w = fmaxf(rmax0.w, acc0.w);
            rmax1.x = fmaxf(rmax1.x, acc1.x); rmax1.y = fmaxf(rmax1.y, acc1.y);
            rmax1.z = fmaxf(rmax1.z, acc1.z); rmax1.w = fmaxf(rmax1.w, acc1.w);
            rmax2.x = fmaxf(rmax2.x, acc2.x); rmax2.y = fmaxf(rmax2.y, acc2.y);
            rmax2.z = fmaxf(rmax2.z, acc2.z); rmax2.w = fmaxf(rmax2.w, acc2.w);
            rmax3.x = fmaxf(rmax3.x, acc3.x); rmax3.y = fmaxf(rmax3.y, acc3.y);
            rmax3.z = fmaxf(rmax3.z, acc3.z); rmax3.w = fmaxf(rmax3.w, acc3.w);
        }

        // reduce 16 edge-rows: 4 regs in-lane, then across the 4 lane-groups (same col)
        float v0 = fmaxf(fmaxf(rmax0.x, rmax0.y), fmaxf(rmax0.z, rmax0.w));
        float v1 = fmaxf(fmaxf(rmax1.x, rmax1.y), fmaxf(rmax1.z, rmax1.w));
        float v2 = fmaxf(fmaxf(rmax2.x, rmax2.y), fmaxf(rmax2.z, rmax2.w));
        float v3 = fmaxf(fmaxf(rmax3.x, rmax3.y), fmaxf(rmax3.z, rmax3.w));
        v0 = fmaxf(v0, __shfl_xor(v0, 16)); v0 = fmaxf(v0, __shfl_xor(v0, 32));
        v1 = fmaxf(v1, __shfl_xor(v1, 16)); v1 = fmaxf(v1, __shfl_xor(v1, 32));
        v2 = fmaxf(v2, __shfl_xor(v2, 16)); v2 = fmaxf(v2, __shfl_xor(v2, 32));
        v3 = fmaxf(v3, __shfl_xor(v3, 16)); v3 = fmaxf(v3, __shfl_xor(v3, 32));
        float vs = (lane & 32) ? ((lane & 16) ? v3 : v2) : ((lane & 16) ? v1 : v0);
        cat[(size_t)n * 192 + colofs + lane] = fmaxf(vs + b2j, 0.f);
    }
}

// ============================ graph mean pool ============================
__global__ void pool_kernel(const float* __restrict__ cat, const int* __restrict__ batch,
                            float* __restrict__ pooled) {
    __shared__ int se[2];
    int g = blockIdx.x, tid = threadIdx.x;  // 192 threads
    if (tid < 2) {
        int target = g + tid;
        int lo = 0, hi = N_NODES;
        while (lo < hi) { int mid = (lo + hi) >> 1; if (batch[mid] < target) lo = mid + 1; else hi = mid; }
        se[tid] = lo;
    }
    __syncthreads();
    int s = se[0], e = se[1];
    float acc = 0.f;
    for (int r = s; r < e; r++) acc += cat[(size_t)r * 192 + tid];
    float denom = (e > s) ? (float)(e - s) : 1.0f;
    pooled[g * 192 + tid] = acc / denom;
}

// ============================ MLP head + log_softmax ============================
__global__ __launch_bounds__(128) void head_kernel(const float* __restrict__ pooled,
                                                   const float* __restrict__ fc1w,
                                                   const float* __restrict__ fc1b,
                                                   const float* __restrict__ fc2w,
                                                   const float* __restrict__ fc2b,
                                                   float* __restrict__ out) {
    __shared__ float p[192];
    __shared__ float hid[128];
    __shared__ float z[10];
    __shared__ float lse;
    int g = blockIdx.x, tid = threadIdx.x;
    for (int i = tid; i < 192; i += 128) p[i] = pooled[g * 192 + i];
    __syncthreads();
    float acc = fc1b[tid];
    for (int k = 0; k < 192; k++) acc = fmaf(p[k], fc1w[k * 128 + tid], acc);
    hid[tid] = fmaxf(acc, 0.f);
    __syncthreads();
    if (tid < N_CLASSES) {
        float a = fc2b[tid];
        for (int k = 0; k < 128; k++) a = fmaf(hid[k], fc2w[k * 10 + tid], a);
        z[tid] = a;
    }
    __syncthreads();
    if (tid == 0) {
        float m = z[0];
        for (int i = 1; i < 10; i++) m = fmaxf(m, z[i]);
        float s = 0.f;
        for (int i = 0; i < 10; i++) s += expf(z[i] - m);
        lse = m + logf(s);
    }
    __syncthreads();
    if (tid < N_CLASSES) out[g * 10 + tid] = z[tid] - lse;
}

// ============================ launch ============================
extern "C" void kernel_launch(void* const* d_in, const int* in_sizes, int n_in,
                              void* d_out, int out_size, void* d_ws, size_t ws_size,
                              hipStream_t stream) {
    (void)in_sizes; (void)n_in; (void)out_size; (void)ws_size;
    const float* x    = (const float*)d_in[0];
    const int*   ei   = (const int*)d_in[1];
    const int*   batch= (const int*)d_in[2];
    const float* fc0w = (const float*)d_in[3];
    const float* fc0b = (const float*)d_in[4];
    const float* fc1w = (const float*)d_in[5];
    const float* fc1b = (const float*)d_in[6];
    const float* fc2w = (const float*)d_in[7];
    const float* fc2b = (const float*)d_in[8];
    const int* src = ei;
    const int* dst = ei + N_EDGES;
    float* out = (float*)d_out;

    char* w = (char*)d_ws;
    size_t off = 0;
    auto alloc = [&](size_t bytes) -> void* {
        void* p = w + off;
        off = (off + bytes + 255) & ~(size_t)255;
        return p;
    };
    const size_t MAX_PAD_EDGES = (size_t)N_EDGES + 16 * (size_t)N_NODES;
    float* cat     = (float*)alloc((size_t)N_NODES * 192 * 4);   // 38.4 MB
    float* h0      = (float*)alloc((size_t)N_NODES * 64 * 4);    // 12.8 MB
    float* Ae      = (float*)alloc((size_t)N_NODES * 64 * 4);    // 12.8 MB
    unsigned short* Be = (unsigned short*)alloc((size_t)N_NODES * 64 * 2);  // 6.4 MB (bf16)
    unsigned* keys = (unsigned*)alloc((size_t)N_EDGES * 4);      // 6.4 MB
    unsigned short* sorted_src = (unsigned short*)alloc(MAX_PAD_EDGES * 2);  // 4.8 MB
    int*   cnt     = (int*)alloc((size_t)N_NODES * 4);
    int*   row_start = (int*)alloc((size_t)(N_NODES + 1) * 4);
    int*   bucket_cnt = (int*)alloc(NB * 4);
    int*   bucket_start = (int*)alloc((NB + 1) * 4);
    int*   gcur    = (int*)alloc(NB * 4);
    int*   blocksum  = (int*)alloc(64 * 4);
    float* bns     = (float*)alloc(128 * 4);
    float* WA      = (float*)alloc(4096 * 4);
    float* WB      = (float*)alloc(4096 * 4);
    float* cAB     = (float*)alloc(128 * 4);
    float* pooled  = (float*)alloc((size_t)N_GRAPHS * 192 * 4);

    // --- two-level counting sort: edges -> padded CSR by dst ---
    hipMemsetAsync(bucket_cnt, 0, NB * 4, stream);
    precount_kernel<<<256, 256, 0, stream>>>(dst, bucket_cnt);
    bucket_scan_kernel<<<1, 256, 0, stream>>>(bucket_cnt, bucket_start, gcur);
    pass1_kernel<<<(N_EDGES + CHUNK - 1) / CHUNK, 256, 0, stream>>>(src, dst, gcur, keys);
    node_count_kernel<<<NB, 256, 0, stream>>>(keys, bucket_start, cnt);
    scan1_kernel<<<49, 1024, 0, stream>>>(cnt, row_start, blocksum);
    scan2_kernel<<<1, 64, 0, stream>>>(blocksum, 49, row_start);
    scan3_kernel<<<49, 1024, 0, stream>>>(row_start, blocksum);
    pass2_kernel<<<NB, 256, 0, stream>>>(keys, bucket_start, row_start, sorted_src);

    fc0_kernel<<<1024, 256, 0, stream>>>(x, fc0w, fc0b, h0);

    for (int blk = 0; blk < 3; blk++) {
        const float* g  = (const float*)d_in[9 + 6 * blk];
        const float* bb = (const float*)d_in[10 + 6 * blk];
        const float* w1 = (const float*)d_in[11 + 6 * blk];
        const float* b1 = (const float*)d_in[12 + 6 * blk];
        const float* w2 = (const float*)d_in[13 + 6 * blk];
        const float* b2 = (const float*)d_in[14 + 6 * blk];
        const float* hsrc = (blk == 0) ? h0 : (cat + (blk - 1) * 64);
        int ldh = (blk == 0) ? 64 : 192;

        hipMemsetAsync(bns, 0, 128 * 4, stream);
        bnstat_kernel<<<512, 256, 0, stream>>>(hsrc, ldh, bns);
        prep_kernel<<<1, 64, 0, stream>>>(bns, g, bb, w1, b1, WA, WB, cAB);
        ab_kernel<<<1024, 256, 0, stream>>>(hsrc, ldh, WA, WB, cAB, Ae, Be);
        edge_mfma_kernel<<<2048, 256, 0, stream>>>(Ae, Be, row_start, sorted_src, w2, b2, cat, blk * 64);
    }

    pool_kernel<<<N_GRAPHS, 192, 0, stream>>>(cat, batch, pooled);
    head_kernel<<<N_GRAPHS, 128, 0, stream>>>(pooled, fc1w, fc1b, fc2w, fc2b, out);
}